// Round 2
// baseline (1637.190 us; speedup 1.0000x reference)
//
#include <hip/hip_runtime.h>
#include <math.h>

#define NV 163842
#define NE 983052

// order-preserving float->uint transform (descending top-k: larger value -> larger key)
static __device__ __forceinline__ unsigned ordf(float f){
  unsigned u = __float_as_uint(f);
  return (u & 0x80000000u) ? ~u : (u | 0x80000000u);
}

// ---- aggregation (input-feature dim, compacted edges) ----

__global__ void scatter_deg_c(const int* __restrict__ dst, const int* __restrict__ cnt,
                              int m_static, float* __restrict__ deg){
  int m = cnt ? cnt[0] : m_static;
  int stride = gridDim.x*blockDim.x;
  for(int e = blockIdx.x*blockDim.x+threadIdx.x; e<m; e+=stride)
    atomicAdd(&deg[dst[e]], 1.0f);
}

// g = h * 1/(deg+1)  (self-loop term), then scatter adds on top
__global__ void init_g(const float* __restrict__ h, const float* __restrict__ deg,
                       float* __restrict__ g, long long total, int fshift){
  long long t = (long long)blockIdx.x*blockDim.x+threadIdx.x;
  if(t>=total) return;
  int r = (int)(t>>fshift);
  g[t] = h[t] * (1.0f/(deg[r]+1.0f));
}

// g[dst] += h[src] * rsqrt(deg_s+1)*rsqrt(deg_d+1); thread per (edge, float4-quad)
__global__ void scatter_agg_c(const int* __restrict__ src, const int* __restrict__ dst,
                              const int* __restrict__ cnt, int m_static,
                              const float* __restrict__ deg, const float* __restrict__ h,
                              float* __restrict__ g, int Fi, int qshift){
  int m = cnt ? cnt[0] : m_static;
  long long total = (long long)m << qshift;
  long long stride = (long long)gridDim.x*blockDim.x;
  int qmask = (1<<qshift)-1;
  for(long long t = (long long)blockIdx.x*blockDim.x+threadIdx.x; t<total; t+=stride){
    int e = (int)(t >> qshift);
    int q = ((int)t) & qmask;
    int s = src[e], d = dst[e];
    float norm = rsqrtf(deg[s]+1.0f)*rsqrtf(deg[d]+1.0f);
    const float4 hv = *(const float4*)(h + (size_t)s*Fi + (size_t)q*4);
    float* gp = g + (size_t)d*Fi + (size_t)q*4;
    atomicAdd(gp+0, hv.x*norm);
    atomicAdd(gp+1, hv.y*norm);
    atomicAdd(gp+2, hv.z*norm);
    atomicAdd(gp+3, hv.w*norm);
  }
}

// hfull = relu(g @ W + b); thread computes one output column for 16 consecutive rows
__global__ void matmul_relu(const float* __restrict__ h, const float* __restrict__ W,
                            const float* __restrict__ b, float* __restrict__ out,
                            int n, int Fi, int Fo, int shift){
  long long t = (long long)blockIdx.x*blockDim.x + threadIdx.x;
  int c = (int)(t & (Fo-1));
  int rb = (int)(t >> shift) * 16;
  if(rb >= n) return;
  float acc[16];
  #pragma unroll
  for(int j=0;j<16;j++) acc[j]=0.f;
  int rows = n - rb; if(rows>16) rows=16;
  if(rows==16){
    for(int i=0;i<Fi;i++){
      float w = W[(size_t)i*Fo + c];
      const float* hp = h + (size_t)rb*Fi + i;
      #pragma unroll
      for(int j=0;j<16;j++) acc[j] = fmaf(hp[(size_t)j*Fi], w, acc[j]);
    }
  } else {
    for(int i=0;i<Fi;i++){
      float w = W[(size_t)i*Fo + c];
      const float* hp = h + (size_t)rb*Fi + i;
      for(int j=0;j<rows;j++) acc[j] = fmaf(hp[(size_t)j*Fi], w, acc[j]);
    }
  }
  float bc = b[c];
  for(int j=0;j<rows;j++){
    float v = acc[j] + bc;
    out[(size_t)(rb+j)*Fo + c] = v>0.f ? v : 0.f;
  }
}

// score[i] = tanh((h[i,:].p) * rsqrt(p.p)); ||p|| computed per block (F <= 256)
__global__ void score2(const float* __restrict__ h, int n, int F,
                       const float* __restrict__ p, float* __restrict__ score){
  __shared__ float red[4];
  __shared__ float pninv;
  float pe = (threadIdx.x < F) ? p[threadIdx.x] : 0.f;
  float s = pe*pe;
  for(int o=32;o;o>>=1) s += __shfl_down(s,o,64);
  int lane=threadIdx.x&63, w=threadIdx.x>>6;
  if(lane==0) red[w]=s;
  __syncthreads();
  if(threadIdx.x==0) pninv = rsqrtf(red[0]+red[1]+red[2]+red[3]);
  __syncthreads();
  int wid = blockIdx.x*4 + w;
  if(wid>=n) return;
  const float* row = h + (size_t)wid*F;
  float d=0.f;
  for(int f=lane; f<F; f+=64) d = fmaf(row[f], p[f], d);
  for(int o=32;o;o>>=1) d += __shfl_down(d,o,64);
  if(lane==0) score[wid] = tanhf(d*pninv);
}

// exact k-th largest via 4-pass byte radix select; out: ordf-threshold + tie quota
__global__ void radix_select(const float* __restrict__ score, int n, int k,
                             unsigned* __restrict__ out_thr, int* __restrict__ out_q){
  __shared__ int hist[256];
  __shared__ unsigned pref;
  __shared__ int rank;
  if(threadIdx.x==0){ pref=0u; rank=k; }
  __syncthreads();
  for(int b=3;b>=0;b--){
    if(threadIdx.x<256) hist[threadIdx.x]=0;
    __syncthreads();
    unsigned p = pref;
    for(int i=threadIdx.x;i<n;i+=blockDim.x){
      unsigned o = ordf(score[i]);
      bool match = (b==3) || (((o ^ p) >> ((b+1)*8)) == 0);
      if(match) atomicAdd(&hist[(o>>(b*8))&255],1);
    }
    __syncthreads();
    if(threadIdx.x==0){
      int running=0; int d;
      for(d=255;d>0;d--){
        if(running + hist[d] >= rank) break;
        running += hist[d];
      }
      pref |= ((unsigned)d) << (b*8);
      rank -= running;
    }
    __syncthreads();
  }
  if(threadIdx.x==0){ out_thr[0]=pref; out_q[0]=rank; }
}

__global__ void sel_blockcount(const float* __restrict__ score, int n,
                               const unsigned* __restrict__ thr,
                               int* __restrict__ blkGt, int* __restrict__ blkEq){
  int i = blockIdx.x*256 + threadIdx.x;
  unsigned vthr = thr[0];
  int gt=0, eq=0;
  if(i<n){ unsigned o=ordf(score[i]); gt = (o>vthr); eq = (o==vthr); }
  unsigned long long bg=__ballot(gt), be=__ballot(eq);
  __shared__ int sg[4], se[4];
  int lane=threadIdx.x&63, w=threadIdx.x>>6;
  if(lane==0){ sg[w]=__popcll(bg); se[w]=__popcll(be); }
  __syncthreads();
  if(threadIdx.x==0){
    int g=0,e=0;
    for(int j=0;j<4;j++){ g+=sg[j]; e+=se[j]; }
    blkGt[blockIdx.x]=g; blkEq[blockIdx.x]=e;
  }
}

__global__ void scan_offsets(int* blkGt, int* blkEq, int nb){
  if(threadIdx.x==0 && blockIdx.x==0){
    int g=0,e=0;
    for(int j=0;j<nb;j++){ int tg=blkGt[j], te=blkEq[j]; blkGt[j]=g; blkEq[j]=e; g+=tg; e+=te; }
  }
}

__global__ void compact(const float* __restrict__ score, int n,
                        const unsigned* __restrict__ thr, const int* __restrict__ qp,
                        const int* __restrict__ blkGt, const int* __restrict__ blkEq,
                        int* __restrict__ newidx, int* __restrict__ oldidx){
  int i = blockIdx.x*256 + threadIdx.x;
  unsigned vthr = thr[0];
  int q = qp[0];
  int gt=0, eq=0;
  if(i<n){ unsigned o=ordf(score[i]); gt=(o>vthr); eq=(o==vthr); }
  unsigned long long bg=__ballot(gt), be=__ballot(eq);
  int lane=threadIdx.x&63, w=threadIdx.x>>6;
  unsigned long long mask = lane ? (~0ull >> (64-lane)) : 0ull;
  int pg = __popcll(bg & mask), pe = __popcll(be & mask);
  __shared__ int sg[4], se[4];
  if(lane==63){ sg[w]=pg+gt; se[w]=pe+eq; }
  __syncthreads();
  int wg=0,we=0;
  for(int j=0;j<w;j++){ wg+=sg[j]; we+=se[j]; }
  if(i<n){
    int gtp = blkGt[blockIdx.x] + wg + pg;
    int eqp = blkEq[blockIdx.x] + we + pe;
    int sel = gt || (eq && (eqp < q));
    if(sel){
      int pos = gtp + (eqp < q ? eqp : q);  // rank among selected, by original index
      newidx[i]=pos; oldidx[pos]=i;
    } else newidx[i]=-1;
  }
}

__global__ void gather_scale(const float* __restrict__ hfull, const float* __restrict__ score,
                             const int* __restrict__ oldidx, float* __restrict__ hout,
                             int k, int Fo, int shift){
  long long t = (long long)blockIdx.x*blockDim.x + threadIdx.x;
  int nr = (int)(t >> shift);
  if(nr >= k) return;
  int f = (int)(t & (Fo-1));
  int old = oldidx[nr];
  hout[t] = hfull[(size_t)old*Fo+f] * score[old];
}

// remap surviving edges into a compacted list for the next layer
__global__ void remap_compact(const int* __restrict__ src, const int* __restrict__ dst,
                              const int* __restrict__ cnt_in, int m_static,
                              const int* __restrict__ newidx,
                              int* __restrict__ osrc, int* __restrict__ odst,
                              int* __restrict__ cnt_out){
  int m = cnt_in ? cnt_in[0] : m_static;
  int stride = gridDim.x*blockDim.x;
  for(int e = blockIdx.x*blockDim.x+threadIdx.x; e<m; e+=stride){
    int ns = newidx[src[e]], nd = newidx[dst[e]];
    if(ns>=0 && nd>=0){
      int pos = atomicAdd(cnt_out, 1);
      osrc[pos]=ns; odst[pos]=nd;
    }
  }
}

// per-feature max & mean over final nodes; xc[0:256]=max, xc[256:512]=mean
__global__ void pool_kernel(const float* __restrict__ h, int n, float* __restrict__ xc){
  int f = blockIdx.x;
  float mx = -3.402823466e38f, sm=0.f;
  for(int r=threadIdx.x; r<n; r+=blockDim.x){
    float v = h[(size_t)r*256+f];
    mx = fmaxf(mx,v); sm += v;
  }
  __shared__ float smx[4], ssm[4];
  for(int o=32;o;o>>=1){ mx=fmaxf(mx,__shfl_down(mx,o,64)); sm+=__shfl_down(sm,o,64); }
  int lane=threadIdx.x&63, w=threadIdx.x>>6;
  if(lane==0){ smx[w]=mx; ssm[w]=sm; }
  __syncthreads();
  if(threadIdx.x==0){
    for(int j=1;j<4;j++){ mx=fmaxf(mx,smx[j]); sm+=ssm[j]; }
    xc[f]=mx; xc[256+f]=sm/(float)n;
  }
}

__global__ void fc_kernel(const float* __restrict__ xc, const float* __restrict__ fcw,
                          const float* __restrict__ fcb, const float* __restrict__ fc2w,
                          const float* __restrict__ fc2b, float* __restrict__ out){
  __shared__ float x[512];
  for(int i=threadIdx.x;i<512;i+=256) x[i]=xc[i];
  __syncthreads();
  int j=threadIdx.x;
  float a=fcb[j];
  for(int i=0;i<512;i++) a = fmaf(x[i], fcw[(size_t)j*512+i], a);
  a = a>0.f ? a : 0.f;
  float v = a*fc2w[j];
  for(int o=32;o;o>>=1) v += __shfl_down(v,o,64);
  __shared__ float sv[4];
  int lane=threadIdx.x&63, w=threadIdx.x>>6;
  if(lane==0) sv[w]=v;
  __syncthreads();
  if(threadIdx.x==0) out[0]=sv[0]+sv[1]+sv[2]+sv[3]+fc2b[0];
}

extern "C" void kernel_launch(void* const* d_in, const int* in_sizes, int n_in,
                              void* d_out, int out_size, void* d_ws, size_t ws_size,
                              hipStream_t stream) {
  const float* x   = (const float*)d_in[0];
  const int*   ei  = (const int*)d_in[1];
  const float* Wm[4] = {(const float*)d_in[2],(const float*)d_in[5],(const float*)d_in[8],(const float*)d_in[11]};
  const float* bv[4] = {(const float*)d_in[3],(const float*)d_in[6],(const float*)d_in[9],(const float*)d_in[12]};
  const float* pv[4] = {(const float*)d_in[4],(const float*)d_in[7],(const float*)d_in[10],(const float*)d_in[13]};
  const float* fcw  = (const float*)d_in[14];
  const float* fcb  = (const float*)d_in[15];
  const float* fc2w = (const float*)d_in[16];
  const float* fc2b = (const float*)d_in[17];

  char* base = (char*)d_ws; size_t off=0;
  auto alloc = [&](size_t bytes)->void*{
    void* p = base + off; off += (bytes + 511) & ~(size_t)511; return p;
  };
  int*   es1    = (int*)  alloc((size_t)NE*4);
  int*   ed1    = (int*)  alloc((size_t)NE*4);
  int*   es2    = (int*)  alloc((size_t)NE*4);
  int*   ed2    = (int*)  alloc((size_t)NE*4);
  float* deg    = (float*)alloc((size_t)NV*4);
  float* score  = (float*)alloc((size_t)NV*4);
  int*   newidx = (int*)  alloc((size_t)NV*4);
  int*   oldidx = (int*)  alloc((size_t)NV*4);
  float* g      = (float*)alloc((size_t)2621568*4);
  float* hfull  = (float*)alloc((size_t)5243136*4);
  float* hbuf   = (float*)alloc((size_t)2621696*4);
  int*   cnt    = (int*)  alloc(64);      // edge counts produced by layers 0..2
  unsigned* thr = (unsigned*)alloc(64);
  int*   qv     = (int*)  alloc(64);
  int*   blkGt  = (int*)  alloc(4096);
  int*   blkEq  = (int*)  alloc(4096);
  float* xc     = (float*)alloc(2048);
  if (off > ws_size) return;

  const int ns[5]   = {163842, 81921, 40961, 20481, 10241};
  const int dims[5] = {4, 32, 64, 128, 256};
  const int foshf[4]= {5, 6, 7, 8};     // log2(Fo)
  const int fishf[4]= {2, 5, 6, 7};     // log2(Fi)
  const int qshf[4] = {0, 3, 4, 5};     // log2(Fi/4)

  hipMemsetAsync(cnt, 0, 16, stream);

  const int* curS[4] = {ei,      es1, es2, es1};
  const int* curD[4] = {ei + NE, ed1, ed2, ed1};
  int*       outS[3] = {es1, es2, es1};
  int*       outD[3] = {ed1, ed2, ed1};

  const float* hin = x;
  for(int l=0;l<4;l++){
    int n=ns[l], k=ns[l+1], Fi=dims[l], Fo=dims[l+1];
    const int* cin = (l==0) ? nullptr : (cnt + (l-1));
    hipMemsetAsync(deg, 0, (size_t)n*4, stream);
    // degree
    unsigned dgrid = (l==0) ? (NE+255)/256 : 1024;
    scatter_deg_c<<<dgrid,256,0,stream>>>(curD[l], cin, NE, deg);
    // g = h/(deg+1) + scatter(h[src]*norm)
    long long nf = (long long)n*Fi;
    init_g<<<(unsigned)((nf+255)/256),256,0,stream>>>(hin, deg, g, nf, fishf[l]);
    unsigned agrid = (l==0) ? (unsigned)(((long long)NE+255)/256) : 2048;
    scatter_agg_c<<<agrid,256,0,stream>>>(curS[l], curD[l], cin, NE, deg, hin, g, Fi, qshf[l]);
    // hfull = relu(g@W + b)
    long long rbc = (n+15)/16;
    matmul_relu<<<(unsigned)((rbc*Fo+255)/256),256,0,stream>>>(g, Wm[l], bv[l], hfull, n, Fi, Fo, foshf[l]);
    // top-k pooling
    score2<<<(n+3)/4,256,0,stream>>>(hfull, n, Fo, pv[l], score);
    radix_select<<<1,1024,0,stream>>>(score, n, k, thr, qv);
    int nb = (n+255)/256;
    sel_blockcount<<<nb,256,0,stream>>>(score, n, thr, blkGt, blkEq);
    scan_offsets<<<1,64,0,stream>>>(blkGt, blkEq, nb);
    compact<<<nb,256,0,stream>>>(score, n, thr, qv, blkGt, blkEq, newidx, oldidx);
    gather_scale<<<(unsigned)((((long long)k*Fo)+255)/256),256,0,stream>>>(hfull, score, oldidx, hbuf, k, Fo, foshf[l]);
    if(l<3){
      unsigned rgrid = (l==0) ? (NE+255)/256 : 1024;
      remap_compact<<<rgrid,256,0,stream>>>(curS[l], curD[l], cin, NE, newidx, outS[l], outD[l], cnt + l);
    }
    hin = hbuf;
  }

  pool_kernel<<<256,256,0,stream>>>(hbuf, ns[4], xc);
  fc_kernel<<<1,256,0,stream>>>(xc, fcw, fcb, fc2w, fc2b, (float*)d_out);
}

// Round 3
// 1242.301 us; speedup vs baseline: 1.3179x; 1.3179x over previous
//
#include <hip/hip_runtime.h>
#include <math.h>

#define NV 163842
#define NE 983052

// order-preserving float->uint transform (descending top-k: larger value -> larger key)
static __device__ __forceinline__ unsigned ordf(float f){
  unsigned u = __float_as_uint(f);
  return (u & 0x80000000u) ? ~u : (u | 0x80000000u);
}

// ---------------- CSR build ----------------

__global__ void deg_count(const int* __restrict__ dst, const int* __restrict__ cnt,
                          int m_static, int* __restrict__ degi){
  int m = cnt ? cnt[0] : m_static;
  int stride = gridDim.x*blockDim.x;
  for(int e = blockIdx.x*blockDim.x+threadIdx.x; e<m; e+=stride)
    atomicAdd(&degi[dst[e]], 1);
}

// per-256-block sums of degi
__global__ void block_sums(const int* __restrict__ degi, int n, int* __restrict__ bsum){
  int i = blockIdx.x*256 + threadIdx.x;
  int v = (i<n) ? degi[i] : 0;
  for(int o=32;o;o>>=1) v += __shfl_down(v,o,64);
  __shared__ int sg[4];
  int lane=threadIdx.x&63, w=threadIdx.x>>6;
  if(lane==0) sg[w]=v;
  __syncthreads();
  if(threadIdx.x==0) bsum[blockIdx.x]=sg[0]+sg[1]+sg[2]+sg[3];
}

// in-place exclusive scan of bsum[0..nb), single block, chunked LDS scan
__global__ void scan_bsums(int* __restrict__ bsum, int nb){
  __shared__ int sh[256];
  __shared__ int carry;
  if(threadIdx.x==0) carry=0;
  __syncthreads();
  for(int base=0;base<nb;base+=256){
    int i = base+threadIdx.x;
    int v = (i<nb) ? bsum[i] : 0;
    sh[threadIdx.x]=v;
    __syncthreads();
    for(int o=1;o<256;o<<=1){
      int t = (threadIdx.x>=o) ? sh[threadIdx.x-o] : 0;
      __syncthreads();
      sh[threadIdx.x]+=t;
      __syncthreads();
    }
    int incl = sh[threadIdx.x];
    int c = carry;
    if(i<nb) bsum[i] = incl - v + c;
    __syncthreads();
    if(threadIdx.x==255) carry = c + incl;
    __syncthreads();
  }
}

// rowptr[i] = exclusive scan of degi (+ block offset); also cursor copy and dinv
__global__ void scan_local(const int* __restrict__ degi, const int* __restrict__ bofs,
                           int n, int* __restrict__ rowptr, int* __restrict__ cursor,
                           float* __restrict__ dinv){
  __shared__ int sh[256];
  int i = blockIdx.x*256 + threadIdx.x;
  int v = (i<n) ? degi[i] : 0;
  sh[threadIdx.x]=v;
  __syncthreads();
  for(int o=1;o<256;o<<=1){
    int t = (threadIdx.x>=o) ? sh[threadIdx.x-o] : 0;
    __syncthreads();
    sh[threadIdx.x]+=t;
    __syncthreads();
  }
  if(i<n){
    int excl = sh[threadIdx.x] - v + bofs[blockIdx.x];
    rowptr[i]=excl; cursor[i]=excl;
    dinv[i] = rsqrtf((float)v + 1.0f);
  }
}

__global__ void csr_fill(const int* __restrict__ src, const int* __restrict__ dst,
                         const int* __restrict__ cnt, int m_static,
                         int* __restrict__ cursor, int* __restrict__ csr){
  int m = cnt ? cnt[0] : m_static;
  int stride = gridDim.x*blockDim.x;
  for(int e = blockIdx.x*blockDim.x+threadIdx.x; e<m; e+=stride){
    int pos = atomicAdd(&cursor[dst[e]], 1);
    csr[pos] = src[e];
  }
}

// g[d,f] = dinv[d] * ( h[d,f]*dinv[d] + sum_{s in N(d)} h[s,f]*dinv[s] )
__global__ void csr_gather(const float* __restrict__ h, const float* __restrict__ dinv,
                           const int* __restrict__ rowptr, const int* __restrict__ degi,
                           const int* __restrict__ csr, float* __restrict__ g,
                           int n, int Fi, int fshift){
  long long t = (long long)blockIdx.x*blockDim.x + threadIdx.x;
  int d = (int)(t>>fshift);
  if(d>=n) return;
  int f = (int)t & (Fi-1);
  int start = rowptr[d], deg = degi[d];
  float di = dinv[d];
  float acc = h[(size_t)d*Fi+f]*di;   // self-loop term (pre di scale)
  for(int j=0;j<deg;j++){
    int s = csr[start+j];
    acc = fmaf(h[(size_t)s*Fi+f], dinv[s], acc);
  }
  g[t] = acc*di;
}

// ---------------- dense pieces ----------------

// hfull = relu(g @ W + b); thread computes one output column for 16 consecutive rows
__global__ void matmul_relu(const float* __restrict__ h, const float* __restrict__ W,
                            const float* __restrict__ b, float* __restrict__ out,
                            int n, int Fi, int Fo, int shift){
  long long t = (long long)blockIdx.x*blockDim.x + threadIdx.x;
  int c = (int)(t & (Fo-1));
  int rb = (int)(t >> shift) * 16;
  if(rb >= n) return;
  float acc[16];
  #pragma unroll
  for(int j=0;j<16;j++) acc[j]=0.f;
  int rows = n - rb; if(rows>16) rows=16;
  if(rows==16){
    for(int i=0;i<Fi;i++){
      float w = W[(size_t)i*Fo + c];
      const float* hp = h + (size_t)rb*Fi + i;
      #pragma unroll
      for(int j=0;j<16;j++) acc[j] = fmaf(hp[(size_t)j*Fi], w, acc[j]);
    }
  } else {
    for(int i=0;i<Fi;i++){
      float w = W[(size_t)i*Fo + c];
      const float* hp = h + (size_t)rb*Fi + i;
      for(int j=0;j<rows;j++) acc[j] = fmaf(hp[(size_t)j*Fi], w, acc[j]);
    }
  }
  float bc = b[c];
  for(int j=0;j<rows;j++){
    float v = acc[j] + bc;
    out[(size_t)(rb+j)*Fo + c] = v>0.f ? v : 0.f;
  }
}

// score[i] = tanh((h[i,:].p) * rsqrt(p.p)); 4 rows per block
__global__ void score2(const float* __restrict__ h, int n, int F,
                       const float* __restrict__ p, float* __restrict__ score){
  __shared__ float red[4];
  __shared__ float pninv;
  float pe = (threadIdx.x < F) ? p[threadIdx.x] : 0.f;
  float s = pe*pe;
  for(int o=32;o;o>>=1) s += __shfl_down(s,o,64);
  int lane=threadIdx.x&63, w=threadIdx.x>>6;
  if(lane==0) red[w]=s;
  __syncthreads();
  if(threadIdx.x==0) pninv = rsqrtf(red[0]+red[1]+red[2]+red[3]);
  __syncthreads();
  int wid = blockIdx.x*4 + w;
  if(wid>=n) return;
  const float* row = h + (size_t)wid*F;
  float d=0.f;
  for(int f=lane; f<F; f+=64) d = fmaf(row[f], p[f], d);
  for(int o=32;o;o>>=1) d += __shfl_down(d,o,64);
  if(lane==0) score[wid] = tanhf(d*pninv);
}

// exact k-th largest via 4-pass byte radix select; out: ordf-threshold + tie quota
__global__ void radix_select(const float* __restrict__ score, int n, int k,
                             unsigned* __restrict__ out_thr, int* __restrict__ out_q){
  __shared__ int hist[256];
  __shared__ unsigned pref;
  __shared__ int rank;
  if(threadIdx.x==0){ pref=0u; rank=k; }
  __syncthreads();
  for(int b=3;b>=0;b--){
    if(threadIdx.x<256) hist[threadIdx.x]=0;
    __syncthreads();
    unsigned p = pref;
    for(int i=threadIdx.x;i<n;i+=blockDim.x){
      unsigned o = ordf(score[i]);
      bool match = (b==3) || (((o ^ p) >> ((b+1)*8)) == 0);
      if(match) atomicAdd(&hist[(o>>(b*8))&255],1);
    }
    __syncthreads();
    if(threadIdx.x==0){
      int running=0; int d;
      for(d=255;d>0;d--){
        if(running + hist[d] >= rank) break;
        running += hist[d];
      }
      pref |= ((unsigned)d) << (b*8);
      rank -= running;
    }
    __syncthreads();
  }
  if(threadIdx.x==0){ out_thr[0]=pref; out_q[0]=rank; }
}

__global__ void sel_blockcount(const float* __restrict__ score, int n,
                               const unsigned* __restrict__ thr,
                               int* __restrict__ blkGt, int* __restrict__ blkEq){
  int i = blockIdx.x*256 + threadIdx.x;
  unsigned vthr = thr[0];
  int gt=0, eq=0;
  if(i<n){ unsigned o=ordf(score[i]); gt = (o>vthr); eq = (o==vthr); }
  unsigned long long bg=__ballot(gt), be=__ballot(eq);
  __shared__ int sg[4], se[4];
  int lane=threadIdx.x&63, w=threadIdx.x>>6;
  if(lane==0){ sg[w]=__popcll(bg); se[w]=__popcll(be); }
  __syncthreads();
  if(threadIdx.x==0){
    int g=0,e=0;
    for(int j=0;j<4;j++){ g+=sg[j]; e+=se[j]; }
    blkGt[blockIdx.x]=g; blkEq[blockIdx.x]=e;
  }
}

// parallel exclusive scan of the two per-block count arrays (nb <= 641)
__global__ void scan_pair(int* __restrict__ blkGt, int* __restrict__ blkEq, int nb){
  __shared__ int shg[256], she[256];
  __shared__ int cg, ce;
  if(threadIdx.x==0){ cg=0; ce=0; }
  __syncthreads();
  for(int base=0;base<nb;base+=256){
    int i = base+threadIdx.x;
    int vg = (i<nb)?blkGt[i]:0;
    int ve = (i<nb)?blkEq[i]:0;
    shg[threadIdx.x]=vg; she[threadIdx.x]=ve;
    __syncthreads();
    for(int o=1;o<256;o<<=1){
      int tg = (threadIdx.x>=o)?shg[threadIdx.x-o]:0;
      int te = (threadIdx.x>=o)?she[threadIdx.x-o]:0;
      __syncthreads();
      shg[threadIdx.x]+=tg; she[threadIdx.x]+=te;
      __syncthreads();
    }
    int ig = shg[threadIdx.x], ie = she[threadIdx.x];
    int c0=cg, c1=ce;
    if(i<nb){ blkGt[i]=ig-vg+c0; blkEq[i]=ie-ve+c1; }
    __syncthreads();
    if(threadIdx.x==255){ cg=c0+ig; ce=c1+ie; }
    __syncthreads();
  }
}

__global__ void compact(const float* __restrict__ score, int n,
                        const unsigned* __restrict__ thr, const int* __restrict__ qp,
                        const int* __restrict__ blkGt, const int* __restrict__ blkEq,
                        int* __restrict__ newidx, int* __restrict__ oldidx){
  int i = blockIdx.x*256 + threadIdx.x;
  unsigned vthr = thr[0];
  int q = qp[0];
  int gt=0, eq=0;
  if(i<n){ unsigned o=ordf(score[i]); gt=(o>vthr); eq=(o==vthr); }
  unsigned long long bg=__ballot(gt), be=__ballot(eq);
  int lane=threadIdx.x&63, w=threadIdx.x>>6;
  unsigned long long mask = lane ? (~0ull >> (64-lane)) : 0ull;
  int pg = __popcll(bg & mask), pe = __popcll(be & mask);
  __shared__ int sg[4], se[4];
  if(lane==63){ sg[w]=pg+gt; se[w]=pe+eq; }
  __syncthreads();
  int wg=0,we=0;
  for(int j=0;j<w;j++){ wg+=sg[j]; we+=se[j]; }
  if(i<n){
    int gtp = blkGt[blockIdx.x] + wg + pg;
    int eqp = blkEq[blockIdx.x] + we + pe;
    int sel = gt || (eq && (eqp < q));
    if(sel){
      int pos = gtp + (eqp < q ? eqp : q);  // rank among selected, by original index
      newidx[i]=pos; oldidx[pos]=i;
    } else newidx[i]=-1;
  }
}

__global__ void gather_scale(const float* __restrict__ hfull, const float* __restrict__ score,
                             const int* __restrict__ oldidx, float* __restrict__ hout,
                             int k, int Fo, int shift){
  long long t = (long long)blockIdx.x*blockDim.x + threadIdx.x;
  int nr = (int)(t >> shift);
  if(nr >= k) return;
  int f = (int)(t & (Fo-1));
  int old = oldidx[nr];
  hout[t] = hfull[(size_t)old*Fo+f] * score[old];
}

// remap surviving edges into a compacted list for the next layer
__global__ void remap_compact(const int* __restrict__ src, const int* __restrict__ dst,
                              const int* __restrict__ cnt_in, int m_static,
                              const int* __restrict__ newidx,
                              int* __restrict__ osrc, int* __restrict__ odst,
                              int* __restrict__ cnt_out){
  int m = cnt_in ? cnt_in[0] : m_static;
  int stride = gridDim.x*blockDim.x;
  for(int e = blockIdx.x*blockDim.x+threadIdx.x; e<m; e+=stride){
    int ns = newidx[src[e]], nd = newidx[dst[e]];
    if(ns>=0 && nd>=0){
      int pos = atomicAdd(cnt_out, 1);
      osrc[pos]=ns; odst[pos]=nd;
    }
  }
}

// per-feature max & mean over final nodes; xc[0:256]=max, xc[256:512]=mean
__global__ void pool_kernel(const float* __restrict__ h, int n, float* __restrict__ xc){
  int f = blockIdx.x;
  float mx = -3.402823466e38f, sm=0.f;
  for(int r=threadIdx.x; r<n; r+=blockDim.x){
    float v = h[(size_t)r*256+f];
    mx = fmaxf(mx,v); sm += v;
  }
  __shared__ float smx[4], ssm[4];
  for(int o=32;o;o>>=1){ mx=fmaxf(mx,__shfl_down(mx,o,64)); sm+=__shfl_down(sm,o,64); }
  int lane=threadIdx.x&63, w=threadIdx.x>>6;
  if(lane==0){ smx[w]=mx; ssm[w]=sm; }
  __syncthreads();
  if(threadIdx.x==0){
    for(int j=1;j<4;j++){ mx=fmaxf(mx,smx[j]); sm+=ssm[j]; }
    xc[f]=mx; xc[256+f]=sm/(float)n;
  }
}

__global__ void fc_kernel(const float* __restrict__ xc, const float* __restrict__ fcw,
                          const float* __restrict__ fcb, const float* __restrict__ fc2w,
                          const float* __restrict__ fc2b, float* __restrict__ out){
  __shared__ float x[512];
  for(int i=threadIdx.x;i<512;i+=256) x[i]=xc[i];
  __syncthreads();
  int j=threadIdx.x;
  float a=fcb[j];
  for(int i=0;i<512;i++) a = fmaf(x[i], fcw[(size_t)j*512+i], a);
  a = a>0.f ? a : 0.f;
  float v = a*fc2w[j];
  for(int o=32;o;o>>=1) v += __shfl_down(v,o,64);
  __shared__ float sv[4];
  int lane=threadIdx.x&63, w=threadIdx.x>>6;
  if(lane==0) sv[w]=v;
  __syncthreads();
  if(threadIdx.x==0) out[0]=sv[0]+sv[1]+sv[2]+sv[3]+fc2b[0];
}

extern "C" void kernel_launch(void* const* d_in, const int* in_sizes, int n_in,
                              void* d_out, int out_size, void* d_ws, size_t ws_size,
                              hipStream_t stream) {
  const float* x   = (const float*)d_in[0];
  const int*   ei  = (const int*)d_in[1];
  const float* Wm[4] = {(const float*)d_in[2],(const float*)d_in[5],(const float*)d_in[8],(const float*)d_in[11]};
  const float* bv[4] = {(const float*)d_in[3],(const float*)d_in[6],(const float*)d_in[9],(const float*)d_in[12]};
  const float* pv[4] = {(const float*)d_in[4],(const float*)d_in[7],(const float*)d_in[10],(const float*)d_in[13]};
  const float* fcw  = (const float*)d_in[14];
  const float* fcb  = (const float*)d_in[15];
  const float* fc2w = (const float*)d_in[16];
  const float* fc2b = (const float*)d_in[17];

  char* base = (char*)d_ws; size_t off=0;
  auto alloc = [&](size_t bytes)->void*{
    void* p = base + off; off += (bytes + 511) & ~(size_t)511; return p;
  };
  int*   es1    = (int*)  alloc((size_t)NE*4);
  int*   ed1    = (int*)  alloc((size_t)NE*4);
  int*   es2    = (int*)  alloc((size_t)NE*4);
  int*   ed2    = (int*)  alloc((size_t)NE*4);
  int*   csr    = (int*)  alloc((size_t)NE*4);
  int*   degi   = (int*)  alloc((size_t)NV*4);
  int*   rowptr = (int*)  alloc((size_t)NV*4);
  int*   cursor = (int*)  alloc((size_t)NV*4);
  float* dinv   = (float*)alloc((size_t)NV*4);
  float* score  = (float*)alloc((size_t)NV*4);
  int*   newidx = (int*)  alloc((size_t)NV*4);
  int*   oldidx = (int*)  alloc((size_t)NV*4);
  float* g      = (float*)alloc((size_t)2621568*4);
  float* hfull  = (float*)alloc((size_t)5243136*4);
  float* hbuf   = (float*)alloc((size_t)2621696*4);
  int*   bsum   = (int*)  alloc(4096);
  int*   cnt    = (int*)  alloc(64);
  unsigned* thr = (unsigned*)alloc(64);
  int*   qv     = (int*)  alloc(64);
  int*   blkGt  = (int*)  alloc(4096);
  int*   blkEq  = (int*)  alloc(4096);
  float* xc     = (float*)alloc(2048);
  if (off > ws_size) return;

  const int ns[5]   = {163842, 81921, 40961, 20481, 10241};
  const int dims[5] = {4, 32, 64, 128, 256};
  const int foshf[4]= {5, 6, 7, 8};     // log2(Fo)
  const int fishf[4]= {2, 5, 6, 7};     // log2(Fi)

  hipMemsetAsync(cnt, 0, 16, stream);

  const int* curS[4] = {ei,      es1, es2, es1};
  const int* curD[4] = {ei + NE, ed1, ed2, ed1};
  int*       outS[3] = {es1, es2, es1};
  int*       outD[3] = {ed1, ed2, ed1};

  const float* hin = x;
  for(int l=0;l<4;l++){
    int n=ns[l], k=ns[l+1], Fi=dims[l], Fo=dims[l+1];
    const int* cin = (l==0) ? nullptr : (cnt + (l-1));
    int nb = (n+255)/256;
    // ---- CSR build ----
    hipMemsetAsync(degi, 0, (size_t)n*4, stream);
    unsigned egrid = (l==0) ? 2048 : 1024;
    deg_count<<<egrid,256,0,stream>>>(curD[l], cin, NE, degi);
    block_sums<<<nb,256,0,stream>>>(degi, n, bsum);
    scan_bsums<<<1,256,0,stream>>>(bsum, nb);
    scan_local<<<nb,256,0,stream>>>(degi, bsum, n, rowptr, cursor, dinv);
    csr_fill<<<egrid,256,0,stream>>>(curS[l], curD[l], cin, NE, cursor, csr);
    // ---- aggregation (gather, no atomics) ----
    long long nf = (long long)n*Fi;
    csr_gather<<<(unsigned)((nf+255)/256),256,0,stream>>>(hin, dinv, rowptr, degi, csr, g, n, Fi, fishf[l]);
    // ---- dense: hfull = relu(g@W + b) ----
    long long rbc = (n+15)/16;
    matmul_relu<<<(unsigned)((rbc*Fo+255)/256),256,0,stream>>>(g, Wm[l], bv[l], hfull, n, Fi, Fo, foshf[l]);
    // ---- top-k pooling ----
    score2<<<(n+3)/4,256,0,stream>>>(hfull, n, Fo, pv[l], score);
    radix_select<<<1,1024,0,stream>>>(score, n, k, thr, qv);
    sel_blockcount<<<nb,256,0,stream>>>(score, n, thr, blkGt, blkEq);
    scan_pair<<<1,256,0,stream>>>(blkGt, blkEq, nb);
    compact<<<nb,256,0,stream>>>(score, n, thr, qv, blkGt, blkEq, newidx, oldidx);
    gather_scale<<<(unsigned)((((long long)k*Fo)+255)/256),256,0,stream>>>(hfull, score, oldidx, hbuf, k, Fo, foshf[l]);
    if(l<3){
      remap_compact<<<egrid,256,0,stream>>>(curS[l], curD[l], cin, NE, newidx, outS[l], outD[l], cnt + l);
    }
    hin = hbuf;
  }

  pool_kernel<<<256,256,0,stream>>>(hbuf, ns[4], xc);
  fc_kernel<<<1,256,0,stream>>>(xc, fcw, fcb, fc2w, fc2b, (float*)d_out);
}